// Round 6
// baseline (315.757 us; speedup 1.0000x reference)
//
#include <hip/hip_runtime.h>
#include <hip/hip_bf16.h>
#include <cstdint>

// Problem constants
#define Bn   1024
#define Tn   128
#define En   300
#define Hn   100
#define Vn   50000
#define G4n  400   // 4*H
#define MPn  50048 // V padded to mult of 64
#define NPn  448   // 4H padded to mult of 16 (28 n-tiles)
// gate-column PERMUTATION: jp = 4*u + q  <->  j = q*100 + u  (q = gate i,f,g,o)

typedef __bf16 bf16x8 __attribute__((ext_vector_type(8)));
typedef _Float16 half8 __attribute__((ext_vector_type(8)));
typedef _Float16 half2v __attribute__((ext_vector_type(2)));
typedef float  f32x4  __attribute__((ext_vector_type(4)));

// workspace byte offsets
#define OFF_TABLE  0ull         // f16 [Vn][448] permuted cols   44,800,000
#define OFF_OH16   44800000ull  // f16 [Bn][Tn][Hn]              26,214,400
#define OFF_WFRAG  71014400ull  // uint4 [28 nt][4 kc][64] W_hh B-frags  114,688
#define OFF_WFRAGB 71129088ull  // uint4 [10 kc][28 nt][64] W_ih B-frags 286,720
#define OFF_WFRL   71415808ull  // uint4 [10 kc][7 nt][64] llW B-frags    71,680
#define OFF_LV     71535808ull  // f32 [Bn][Hn]                          409,600
#define OFF_PN     71945408ull  // f32 [Bn][Hn]                          409,600
#define OFF_NEG    72355008ull  // f32 [Bn][Hn]                          409,600

__device__ __forceinline__ float sigf(float x) { return 1.0f / (1.0f + __expf(-x)); }
__device__ __forceinline__ float tanhfast(float x) { return 1.0f - 2.0f / (__expf(2.0f * x) + 1.0f); }

// -------- K0: W_hh -> f16 B-frags; W_ih -> bf16 B-frags; llW -> bf16 B-frags -
__global__ void k_prep(const float* __restrict__ W_ih, const float* __restrict__ W_hh,
                       const float* __restrict__ llW,
                       uint4* __restrict__ wfrag, uint4* __restrict__ wfragB,
                       uint4* __restrict__ wfragL) {
    int idx = blockIdx.x * 256 + threadIdx.x;
    if (idx < 28 * 4 * 64) {  // W_hh frag: lane holds B[n=nt*16+(l&15)][k=kc*32+(l>>4)*8+j]
        int lane = idx & 63, tk = idx >> 6;
        int nt = tk >> 2, kc = tk & 3;
        int n = nt * 16 + (lane & 15);
        int k0 = kc * 32 + (lane >> 4) * 8;
        int q = n & 3, u = n >> 2;
        union { _Float16 h[8]; uint4 v; } pk;
#pragma unroll
        for (int j = 0; j < 8; j++) {
            int k = k0 + j;
            pk.h[j] = (_Float16)((u < Hn && k < Hn) ? W_hh[(size_t)(q * Hn + u) * Hn + k] : 0.0f);
        }
        wfrag[idx] = pk.v;
    }
    if (idx < 10 * 28 * 64) {  // W_ih frag (bf16): kc-major, permuted n
        int lane = idx & 63, tk = idx >> 6;
        int kc = tk / 28, nsg = tk - kc * 28;
        int n = nsg * 16 + (lane & 15);
        int k0 = kc * 32 + (lane >> 4) * 8;
        int q = n & 3, u = n >> 2;
        union { __bf16 h[8]; uint4 v; } pk;
#pragma unroll
        for (int j = 0; j < 8; j++) {
            int k = k0 + j;
            pk.h[j] = (__bf16)((u < Hn && k < En) ? W_ih[(size_t)(q * Hn + u) * En + k] : 0.0f);
        }
        wfragB[idx] = pk.v;
    }
    if (idx < 10 * 7 * 64) {  // llW frag (bf16): B[n=h][k], no permutation
        int lane = idx & 63, tk = idx >> 6;
        int kc = tk / 7, nsg = tk - kc * 7;
        int n = nsg * 16 + (lane & 15);
        int k0 = kc * 32 + (lane >> 4) * 8;
        union { __bf16 h[8]; uint4 v; } pk;
#pragma unroll
        for (int j = 0; j < 8; j++) {
            int k = k0 + j;
            pk.h[j] = (__bf16)((n < Hn && k < En) ? llW[(size_t)n * En + k] : 0.0f);
        }
        wfragL[idx] = pk.v;
    }
}

// -------- K1: table = emb @ W_ih^T + b (permuted cols, f16 out) --------------
__global__ __launch_bounds__(256, 2) void k_table(
    const float* __restrict__ emb, const uint4* __restrict__ wfragB,
    const float* __restrict__ b_ih, const float* __restrict__ b_hh,
    _Float16* __restrict__ table) {
    __shared__ __bf16 a_sh[64][328];   // 41,984 B
    const int tid = threadIdx.x;
    const int mt = blockIdx.x >> 1, nh = blockIdx.x & 1;

#pragma unroll
    for (int it = 0; it < 5; it++) {
        int x = it * 256 + tid;            // 0..1279
        int row = x / 20, seg = x - row * 20;
        int gr = mt * 64 + row;
        const float* ar = emb + (size_t)(gr < Vn ? gr : Vn - 1) * En;
        int c0 = seg * 16;
        union { __bf16 h[16]; bf16x8 v[2]; } pk;
#pragma unroll
        for (int g = 0; g < 4; g++) {
            int c = c0 + g * 4;
            if (c + 4 <= En) {
                float4 f = *(const float4*)(ar + c);
                pk.h[g * 4 + 0] = (__bf16)f.x; pk.h[g * 4 + 1] = (__bf16)f.y;
                pk.h[g * 4 + 2] = (__bf16)f.z; pk.h[g * 4 + 3] = (__bf16)f.w;
            } else {
                pk.h[g * 4 + 0] = (__bf16)0.f; pk.h[g * 4 + 1] = (__bf16)0.f;
                pk.h[g * 4 + 2] = (__bf16)0.f; pk.h[g * 4 + 3] = (__bf16)0.f;
            }
        }
        *(bf16x8*)&a_sh[row][c0] = pk.v[0];
        *(bf16x8*)&a_sh[row][c0 + 8] = pk.v[1];
    }
    __syncthreads();

    const int wv = tid >> 6, l = tid & 63;
    const int c16 = l & 15, quad = l >> 4;
    f32x4 acc[14];
#pragma unroll
    for (int i = 0; i < 14; i++) acc[i] = (f32x4){0.f, 0.f, 0.f, 0.f};

    uint4 bcur[14];
#pragma unroll
    for (int ns = 0; ns < 14; ns++) bcur[ns] = wfragB[((0 * 28 + nh * 14 + ns) << 6) + l];

    for (int kc = 0; kc < 10; kc++) {
        uint4 bnxt[14];
        if (kc < 9) {
#pragma unroll
            for (int ns = 0; ns < 14; ns++) bnxt[ns] = wfragB[(((kc + 1) * 28 + nh * 14 + ns) << 6) + l];
        }
        bf16x8 af = *(const bf16x8*)&a_sh[wv * 16 + c16][kc * 32 + quad * 8];
#pragma unroll
        for (int ns = 0; ns < 14; ns++)
            acc[ns] = __builtin_amdgcn_mfma_f32_16x16x32_bf16(af, __builtin_bit_cast(bf16x8, bcur[ns]), acc[ns], 0, 0, 0);
        if (kc < 9) {
#pragma unroll
            for (int ns = 0; ns < 14; ns++) bcur[ns] = bnxt[ns];
        }
    }
#pragma unroll
    for (int ns = 0; ns < 14; ns++) {
        int n = (nh * 14 + ns) * 16 + c16;
        int q = n & 3, u = n >> 2;
        if (u < Hn) {
            int j = q * Hn + u;
            float bias = b_ih[j] + b_hh[j];
#pragma unroll
            for (int r = 0; r < 4; r++) {
                int m = mt * 64 + wv * 16 + quad * 4 + r;
                if (m < Vn) table[(size_t)m * NPn + n] = (_Float16)(acc[ns][r] + bias);
            }
        }
    }
}

// -------- K2: label_vec via MFMA: lv = emb[lid] @ llW^T + llb ----------------
// 16 blocks x 64 gathered rows; same structure as k_table with 7 n-tiles.
__global__ __launch_bounds__(256, 2) void k_label(
    const int* __restrict__ lwid, const float* __restrict__ emb,
    const uint4* __restrict__ wfragL, const float* __restrict__ llb,
    float* __restrict__ lv) {
    __shared__ __bf16 a_sh[64][328];
    const int tid = threadIdx.x;
    const int b0 = blockIdx.x * 64;

#pragma unroll
    for (int it = 0; it < 5; it++) {
        int x = it * 256 + tid;
        int row = x / 20, seg = x - row * 20;
        int lid = lwid[b0 + row];
        const float* ar = emb + (size_t)lid * En;
        int c0 = seg * 16;
        union { __bf16 h[16]; bf16x8 v[2]; } pk;
#pragma unroll
        for (int g = 0; g < 4; g++) {
            int c = c0 + g * 4;
            if (c + 4 <= En) {
                float4 f = *(const float4*)(ar + c);
                pk.h[g * 4 + 0] = (__bf16)f.x; pk.h[g * 4 + 1] = (__bf16)f.y;
                pk.h[g * 4 + 2] = (__bf16)f.z; pk.h[g * 4 + 3] = (__bf16)f.w;
            } else {
                pk.h[g * 4 + 0] = (__bf16)0.f; pk.h[g * 4 + 1] = (__bf16)0.f;
                pk.h[g * 4 + 2] = (__bf16)0.f; pk.h[g * 4 + 3] = (__bf16)0.f;
            }
        }
        *(bf16x8*)&a_sh[row][c0] = pk.v[0];
        *(bf16x8*)&a_sh[row][c0 + 8] = pk.v[1];
    }
    __syncthreads();

    const int wv = tid >> 6, l = tid & 63;
    const int c16 = l & 15, quad = l >> 4;
    f32x4 acc[7];
#pragma unroll
    for (int i = 0; i < 7; i++) acc[i] = (f32x4){0.f, 0.f, 0.f, 0.f};
    for (int kc = 0; kc < 10; kc++) {
        bf16x8 af = *(const bf16x8*)&a_sh[wv * 16 + c16][kc * 32 + quad * 8];
#pragma unroll
        for (int ns = 0; ns < 7; ns++) {
            bf16x8 bf = __builtin_bit_cast(bf16x8, wfragL[((kc * 7 + ns) << 6) + l]);
            acc[ns] = __builtin_amdgcn_mfma_f32_16x16x32_bf16(af, bf, acc[ns], 0, 0, 0);
        }
    }
#pragma unroll
    for (int ns = 0; ns < 7; ns++) {
        int n = ns * 16 + c16;
        if (n < Hn) {
            float bias = llb[n];
#pragma unroll
            for (int r = 0; r < 4; r++) {
                int m = b0 + wv * 16 + quad * 4 + r;
                lv[(size_t)m * Hn + n] = acc[ns][r] + bias;
            }
        }
    }
}

// -------- K3: fused LSTM, 4 batch/block, 512 thr, MFMA f16 -------------------
// Waves 0-6: 4 n-tiles each (16 MFMA/step); wave 7: scores for step t-1.
// h double-buffered [parity][16 rows][136] (rows 4-15 zero). 2 barriers/step.
__global__ __launch_bounds__(512, 2) void k_lstm(
    const int* __restrict__ word_id, const int* __restrict__ sen_len,
    const _Float16* __restrict__ table, const uint4* __restrict__ wfrag,
    const float* __restrict__ lv, const float* __restrict__ linW,
    const float* __restrict__ linb, _Float16* __restrict__ oh16,
    float* __restrict__ per_neg, float* __restrict__ d_out) {
    __shared__ float    g_sh[4 * 452];      // gates, stride 452 (16B aligned)
    __shared__ _Float16 h_cur[2][16][136];  // [parity][m-row][k]; rows 4-15 zero
    __shared__ float    lt_sh[4][Hn];
    __shared__ float    scores_sh[4][Tn];
    __shared__ int      widc[4][Tn];
    __shared__ float    pos_sh[4][Hn];
    __shared__ float    lasth_sh[4][Hn];
    __shared__ float    tk_val[4][4];
    __shared__ int      tk_idx[4][4];

    const int tid = threadIdx.x;
    const int w = tid >> 6, l = tid & 63;
    const int c16 = l & 15, quad = l >> 4;
    const int b0 = blockIdx.x * 4;

    // init
    for (int i = tid; i < 2 * 16 * 136 / 2; i += 512) ((uint32_t*)h_cur)[i] = 0u;
    if (tid < 400) {
        int imb = tid / 100, iu = tid - imb * 100;
        lt_sh[imb][iu] = lv[(size_t)(b0 + imb) * Hn + iu];
    }
    { int imb = tid >> 7, it = tid & 127; widc[imb][it] = word_id[(b0 + imb) * Tn + it]; }

    // W_hh B-fragments: wave w (0-6) owns n-tiles w*4..w*4+3
    half8 bfr[4][4];
    if (w < 7) {
#pragma unroll
        for (int j = 0; j < 4; j++)
#pragma unroll
            for (int kc = 0; kc < 4; kc++)
                bfr[j][kc] = __builtin_bit_cast(half8, wfrag[((w * 4 + j) * 4 + kc) * 64 + l]);
    }

    // task identity: thread (mb = tid&3, u = tid>>2) for tid < 400
    const int mb = tid & 3, u = tid >> 2;
    const bool act = (tid < 400);
    const int myslen = act ? sen_len[b0 + mb] : 0;
    __syncthreads();

    uint2 xq = {0, 0};
    if (act) xq = *(const uint2*)(table + (size_t)widc[mb][0] * NPn + u * 4);

    float c_reg = 0.f, sumh = 0.f, lasth = 0.f;
    _Float16* ohb_w = oh16 + (size_t)(b0 + mb) * Tn * Hn;

    for (int t = 0; t < Tn; t++) {
        const int pin = t & 1;
        if (w < 7) {
            // ---- MFMA: gates = h . W_hh^T
            const _Float16* hp = &h_cur[pin][0][0];
            f32x4 acc[4];
#pragma unroll
            for (int j = 0; j < 4; j++) acc[j] = (f32x4){0.f, 0.f, 0.f, 0.f};
#pragma unroll
            for (int kc = 0; kc < 4; kc++) {
                half8 af = *(const half8*)(hp + c16 * 136 + kc * 32 + quad * 8);
#pragma unroll
                for (int j = 0; j < 4; j++)
                    acc[j] = __builtin_amdgcn_mfma_f32_16x16x32_f16(af, bfr[j][kc], acc[j], 0, 0, 0);
            }
            if (l < 16) {  // C rows 0-3 (batch) live in quad 0, regs r=0..3
#pragma unroll
                for (int j = 0; j < 4; j++) {
                    int n = (w * 4 + j) * 16 + l;
#pragma unroll
                    for (int r = 0; r < 4; r++) g_sh[r * 452 + n] = acc[j][r];
                }
            }
        } else if (t > 0) {
            // ---- wave 7: scores[t-1] = dot(h_in, label_vec) per mb
            int smb = l & 3, u0 = l >> 2;
            float p = 0.f;
#pragma unroll
            for (int i = 0; i < 7; i++) {
                int uu = u0 + 16 * i;
                if (uu < Hn) p += (float)h_cur[pin][smb][uu] * lt_sh[smb][uu];
            }
            p += __shfl_down(p, 32, 64);
            p += __shfl_down(p, 16, 64);
            p += __shfl_down(p, 8, 64);
            p += __shfl_down(p, 4, 64);
            if (l < 4) scores_sh[smb][t - 1] = p;
        }
        __syncthreads();  // S1: gates ready
        if (act) {
            float4 g4 = *(const float4*)&g_sh[mb * 452 + u * 4];
            half2v x01 = __builtin_bit_cast(half2v, xq.x);
            half2v x23 = __builtin_bit_cast(half2v, xq.y);
            float gi = g4.x + (float)x01.x;
            float gf = g4.y + (float)x01.y;
            float gg = g4.z + (float)x23.x;
            float go = g4.w + (float)x23.y;
            float c = sigf(gf) * c_reg + sigf(gi) * tanhfast(gg);
            c_reg = c;
            float hh = sigf(go) * tanhfast(c);
            h_cur[pin ^ 1][mb][u] = (_Float16)hh;
            ohb_w[t * Hn + u] = (_Float16)hh;
            if (t < myslen) sumh += hh;
            if (t == myslen - 1) lasth = hh;
            int tn = (t + 1 < Tn) ? t + 1 : t;
            xq = *(const uint2*)(table + (size_t)widc[mb][tn] * NPn + u * 4);
        }
        __syncthreads();  // S2: h(t+1) ready
    }
    // ---- score for t = 127 (final h in parity 0)
    if (w == 7) {
        int smb = l & 3, u0 = l >> 2;
        float p = 0.f;
#pragma unroll
        for (int i = 0; i < 7; i++) {
            int uu = u0 + 16 * i;
            if (uu < Hn) p += (float)h_cur[0][smb][uu] * lt_sh[smb][uu];
        }
        p += __shfl_down(p, 32, 64);
        p += __shfl_down(p, 16, 64);
        p += __shfl_down(p, 8, 64);
        p += __shfl_down(p, 4, 64);
        if (l < 4) scores_sh[smb][Tn - 1] = p;
    }
    __syncthreads();
    // ---- top-4: wave k handles mb=k (k<4); tie-break smaller index
    if (w < 4) {
        int kmb = w, lane = l;
        int sl = sen_len[b0 + kmb];
        float s0 = (lane < sl) ? scores_sh[kmb][lane] : -1e30f;
        float s1 = (lane + 64 < sl) ? scores_sh[kmb][lane + 64] : -1e30f;
        bool tk0 = false, tk1 = false;
#pragma unroll
        for (int p4 = 0; p4 < 4; p4++) {
            float v = tk0 ? -1e30f : s0;
            int ix = lane;
            float v1 = tk1 ? -1e30f : s1;
            if (v1 > v) { v = v1; ix = lane + 64; }
            for (int off = 32; off; off >>= 1) {
                float ov = __shfl_down(v, off, 64);
                int oi = __shfl_down(ix, off, 64);
                if (ov > v || (ov == v && oi < ix)) { v = ov; ix = oi; }
            }
            v = __shfl(v, 0, 64);
            ix = __shfl(ix, 0, 64);
            if (lane == 0) { tk_val[kmb][p4] = v; tk_idx[kmb][p4] = ix; }
            if (ix == lane) tk0 = true;
            if (ix == lane + 64) tk1 = true;
        }
    }
    __syncthreads();
    // ---- pos / per_neg / lasth
    if (act) {
        float pos = 0.f, nsum = sumh;
#pragma unroll
        for (int p4 = 0; p4 < 4; p4++) {
            int ix = tk_idx[mb][p4];
            float r = (float)ohb_w[ix * Hn + u];
            pos += tk_val[mb][p4] * r;
            nsum -= r;
        }
        pos_sh[mb][u] = pos;
        lasth_sh[mb][u] = lasth;
        per_neg[(size_t)(b0 + mb) * Hn + u] = nsum;
    }
    __syncthreads();
    // ---- projections: out_f = lin(lasth), l_rep = lin(pos)
    if (tid < 48) {
        int which = tid / 24, r = tid - which * 24;
        int pmb = r / 6, o = r - pmb * 6;
        const float* src = which ? &pos_sh[pmb][0] : &lasth_sh[pmb][0];
        float acc2 = linb[o];
        for (int uu = 0; uu < Hn; uu++) acc2 += src[uu] * linW[o * Hn + uu];
        d_out[(which ? (Bn * 6) : 0) + (b0 + pmb) * 6 + o] = acc2;
    }
}

// -------- K4: batch cumsum of per_neg (wave-shuffle scan) --------------------
__global__ __launch_bounds__(1024) void k_scan(const float* __restrict__ pn, float* __restrict__ neg) {
    __shared__ float wsum[16];
    __shared__ float wpre[16];
    int u = blockIdx.x, t = threadIdx.x;
    int lane = t & 63, wv = t >> 6;
    float v = pn[(size_t)t * Hn + u];
#pragma unroll
    for (int off = 1; off < 64; off <<= 1) {
        float o = __shfl_up(v, off, 64);
        if (lane >= off) v += o;
    }
    if (lane == 63) wsum[wv] = v;
    __syncthreads();
    if (t < 16) {
        float s = wsum[t];
#pragma unroll
        for (int off = 1; off < 16; off <<= 1) {
            float o = __shfl_up(s, off, 64);
            if (t >= off) s += o;
        }
        wpre[t] = s;
    }
    __syncthreads();
    float pre = wv ? wpre[wv - 1] : 0.f;
    neg[(size_t)t * Hn + u] = v + pre;
}

// -------- K5: r_rep = neg @ lin_W^T + lin_b ----------------------------------
__global__ void k_rrep(const float* __restrict__ neg, const float* __restrict__ linW,
                       const float* __restrict__ linb, float* __restrict__ d_out) {
    int gid = blockIdx.x * 256 + threadIdx.x;
    if (gid < Bn * 6) {
        int b = gid / 6, o = gid - b * 6;
        float acc = linb[o];
        for (int u = 0; u < Hn; u++) acc += neg[(size_t)b * Hn + u] * linW[o * Hn + u];
        d_out[2 * Bn * 6 + gid] = acc;
    }
}

extern "C" void kernel_launch(void* const* d_in, const int* in_sizes, int n_in,
                              void* d_out, int out_size, void* d_ws, size_t ws_size,
                              hipStream_t stream) {
    const int*   word_id = (const int*)d_in[0];
    const int*   sen_len = (const int*)d_in[1];
    const int*   lwid    = (const int*)d_in[2];
    const float* emb     = (const float*)d_in[3];
    const float* W_ih    = (const float*)d_in[4];
    const float* W_hh    = (const float*)d_in[5];
    const float* b_ih    = (const float*)d_in[6];
    const float* b_hh    = (const float*)d_in[7];
    const float* linW    = (const float*)d_in[8];
    const float* linb    = (const float*)d_in[9];
    const float* llW     = (const float*)d_in[10];
    const float* llb     = (const float*)d_in[11];

    char* ws = (char*)d_ws;
    _Float16* table  = (_Float16*)(ws + OFF_TABLE);
    _Float16* oh16   = (_Float16*)(ws + OFF_OH16);
    uint4*    wfrag  = (uint4*)(ws + OFF_WFRAG);
    uint4*    wfragB = (uint4*)(ws + OFF_WFRAGB);
    uint4*    wfragL = (uint4*)(ws + OFF_WFRL);
    float*    lvp    = (float*)(ws + OFF_LV);
    float*    pn     = (float*)(ws + OFF_PN);
    float*    neg    = (float*)(ws + OFF_NEG);
    float*    outp   = (float*)d_out;

    k_prep<<<70, 256, 0, stream>>>(W_ih, W_hh, llW, wfrag, wfragB, wfragL);
    k_table<<<(MPn / 64) * 2, 256, 0, stream>>>(emb, wfragB, b_ih, b_hh, table);
    k_label<<<Bn / 64, 256, 0, stream>>>(lwid, emb, wfragL, llb, lvp);
    k_lstm<<<Bn / 4, 512, 0, stream>>>(word_id, sen_len, table, wfrag, lvp, linW, linb, oh16, pn, outp);
    k_scan<<<Hn, 1024, 0, stream>>>(pn, neg);
    k_rrep<<<(Bn * 6 + 255) / 256, 256, 0, stream>>>(neg, linW, linb, outp);
}